// Round 8
// baseline (348.988 us; speedup 1.0000x reference)
//
#include <hip/hip_runtime.h>
#include <math.h>

#define T_LEN 2048
#define BSZ   4
#define EMB   768
#define NH    12
#define DH    64
#define NTOK  (T_LEN * BSZ)      // 8192
#define N_QKV (3 * EMB)          // 2304
#define BH    (BSZ * NH)         // 48
#define CONVB 8448               // (n_x + n_wq + n_wo)/4/256

typedef _Float16 f16;
typedef _Float16 f16x8 __attribute__((ext_vector_type(8)));
typedef _Float16 f16x4 __attribute__((ext_vector_type(4)));
typedef float    f32x4 __attribute__((ext_vector_type(4)));

#define MFMA32(a, b, c) __builtin_amdgcn_mfma_f32_16x16x32_f16(a, b, c, 0, 0, 0)
#define MFMA16(a, b, c) __builtin_amdgcn_mfma_f32_16x16x16f16(a, b, c, 0, 0, 0)

// async global->LDS, 16B per lane; LDS dest = wave-uniform base + lane*16
__device__ __forceinline__ void gload16(const void* g, void* l) {
    __builtin_amdgcn_global_load_lds(
        (const __attribute__((address_space(1))) void*)g,
        (__attribute__((address_space(3))) void*)l, 16, 0, 0);
}

// ---------------------------------------------------------------------------
// Fused: fp32->fp16 conversion (blocks 0..CONVB-1) + mask compaction
// (blocks CONVB..CONVB+BSZ-1, one block of 256 per batch).
// ---------------------------------------------------------------------------
__global__ __launch_bounds__(256) void conv_compact(
    const float* __restrict__ s0, const float* __restrict__ s1,
    const float* __restrict__ s2, f16* __restrict__ dst,
    const int* __restrict__ mask, const float* __restrict__ abias,
    int* __restrict__ cidx, float* __restrict__ cbias,
    int* __restrict__ imap, int* __restrict__ ccount)
{
    const int tid = threadIdx.x;
    if (blockIdx.x < CONVB) {
        const int n0 = NTOK * EMB, n1 = N_QKV * EMB, n2 = EMB * EMB;
        const int i = (blockIdx.x * 256 + tid) * 4;
        const int t01 = n0 + n1;
        const float* s;
        int off;
        if (i < n0)            { s = s0; off = i; }
        else if (i < t01)      { s = s1; off = i - n0; }
        else if (i < t01 + n2) { s = s2; off = i - t01; }
        else return;
        const float4 v = *(const float4*)(s + off);
        f16 hv[4] = {(f16)v.x, (f16)v.y, (f16)v.z, (f16)v.w};
        *(double*)(dst + i) = *(double*)hv;
        return;
    }

    // ---- compaction ----
    const int b = blockIdx.x - CONVB;
    __shared__ int cnt[32], off_l[32], tot[2];
    const int wv = tid >> 6, lane = tid & 63;
    int* ip = cidx + b * T_LEN;
    float* bp = cbias + b * T_LEN;
    int* mp = imap + b * T_LEN;

    for (int i = 0; i < 8; ++i) {
        const int c = wv * 8 + i;
        const int s = c * 64 + lane;
        const int mv = mask[s * BSZ + b];
        const unsigned long long bal = __ballot(mv == 0);
        if (lane == 0) cnt[c] = __popcll(bal);
    }
    __syncthreads();
    if (tid == 0) {
        int acc = 0;
        for (int c = 0; c < 32; ++c) { off_l[c] = acc; acc += cnt[c]; }
        const int npad = (acc + 63) & ~63;
        tot[0] = acc; tot[1] = npad;
        ccount[b] = npad;
    }
    __syncthreads();
    for (int i = 0; i < 8; ++i) {
        const int c = wv * 8 + i;
        const int s = c * 64 + lane;
        const int mv = mask[s * BSZ + b];
        const float bv = abias[s * BSZ + b];
        const unsigned long long bal = __ballot(mv == 0);
        const int pos = __popcll(bal & ((1ull << lane) - 1ull));
        const int basec = off_l[c];
        if (mv == 0) { ip[basec + pos] = s; bp[basec + pos] = bv; mp[s] = basec + pos; }
        else mp[s] = -1;
    }
    const int baseT = tot[0], npad = tot[1];
    if (tid < npad - baseT) { ip[baseT + tid] = 0; bp[baseT + tid] = -1e30f; }
}

// ---------------------------------------------------------------------------
// fp16 MFMA GEMM (m97 structure): global_load_lds(16B), linear LDS [128][32]
// with source-side XOR swizzle, same XOR on frag reads.
// MODE 0: C fp32 MxN.
// MODE 1: q->qb[bh][t][d]*0.125; k->kc[bh][imap(t)][d]; v->vb[bh][t][d]
// ---------------------------------------------------------------------------
template <int MODE>
__global__ __launch_bounds__(256) void gemm_h(
    const f16* __restrict__ A, const f16* __restrict__ W,
    const float* __restrict__ bias, float* __restrict__ C,
    f16* __restrict__ qb, f16* __restrict__ kc, f16* __restrict__ vb,
    const int* __restrict__ imap, int M, int N, int K)
{
    __shared__ __align__(16) f16 As[128][32];
    __shared__ __align__(16) f16 Bs[128][32];

    const int tid = threadIdx.x;
    const int w = tid >> 6, l = tid & 63;
    const int wr = w >> 1, wc = w & 1;
    const int lg = l >> 4, lr = l & 15;

    const int bm = blockIdx.x * 128, bn = blockIdx.y * 128;

    int srow[2], sqc[2];
#pragma unroll
    for (int it = 0; it < 2; ++it) {
        const int c = w * 128 + it * 64 + l;
        srow[it] = c >> 2;
        sqc[it] = (c & 3) ^ ((srow[it] >> 1) & 3);
    }

    f32x4 acc[4][4];
#pragma unroll
    for (int i = 0; i < 4; ++i)
#pragma unroll
        for (int j = 0; j < 4; ++j) acc[i][j] = (f32x4)(0.f);

    const int cq = lg ^ ((lr >> 1) & 3);

    for (int kt = 0; kt < K; kt += 32) {
        __syncthreads();
#pragma unroll
        for (int it = 0; it < 2; ++it) {
            const int ldsb = (w * 128 + it * 64) * 16;
            gload16(A + (size_t)(bm + srow[it]) * K + kt + sqc[it] * 8,
                    (char*)&As[0][0] + ldsb);
            gload16(W + (size_t)(bn + srow[it]) * K + kt + sqc[it] * 8,
                    (char*)&Bs[0][0] + ldsb);
        }
        __syncthreads();

        f16x8 af[4], bf[4];
#pragma unroll
        for (int am = 0; am < 4; ++am)
            af[am] = *(const f16x8*)((const char*)&As[0][0] +
                     (wr * 64 + am * 16 + lr) * 64 + cq * 16);
#pragma unroll
        for (int bnf = 0; bnf < 4; ++bnf)
            bf[bnf] = *(const f16x8*)((const char*)&Bs[0][0] +
                      (wc * 64 + bnf * 16 + lr) * 64 + cq * 16);
#pragma unroll
        for (int am = 0; am < 4; ++am)
#pragma unroll
            for (int bnf = 0; bnf < 4; ++bnf)
                acc[am][bnf] = MFMA32(af[am], bf[bnf], acc[am][bnf]);
    }

    const int colb = bn + wc * 64;
    const int rowb = bm + wr * 64;
    float bv[4];
#pragma unroll
    for (int j = 0; j < 4; ++j) bv[j] = bias[colb + j * 16 + lr];

    if (MODE == 0) {
#pragma unroll
        for (int am = 0; am < 4; ++am)
#pragma unroll
            for (int bnf = 0; bnf < 4; ++bnf)
#pragma unroll
                for (int rg = 0; rg < 4; ++rg) {
                    const int row = rowb + am * 16 + lg * 4 + rg;
                    const int col = colb + bnf * 16 + lr;
                    C[(size_t)row * N + col] = acc[am][bnf][rg] + bv[bnf];
                }
    } else {
        const int sec = bn / EMB;
        const float scale = (sec == 0) ? 0.125f : 1.0f;
#pragma unroll
        for (int bnf = 0; bnf < 4; ++bnf) {
            const int col = colb + bnf * 16 + lr;
            const int e = col - sec * EMB;
            const int h = e >> 6, d = e & 63;
#pragma unroll
            for (int am = 0; am < 4; ++am)
#pragma unroll
                for (int rg = 0; rg < 4; ++rg) {
                    const int row = rowb + am * 16 + lg * 4 + rg;
                    const int t = row >> 2, bb = row & 3;
                    const f16 val = (f16)((acc[am][bnf][rg] + bv[bnf]) * scale);
                    if (sec == 0) {
                        qb[((size_t)((bb * NH + h) * T_LEN + t)) * DH + d] = val;
                    } else if (sec == 1) {
                        const int ipv = imap[bb * T_LEN + t];
                        if (ipv >= 0)
                            kc[((size_t)((bb * NH + h) * T_LEN + ipv)) * DH + d] = val;
                    } else {
                        vb[((size_t)((bb * NH + h) * T_LEN + t)) * DH + d] = val;
                    }
                }
        }
    }
}

// ---------------------------------------------------------------------------
// One-time V gather + transpose: vb[bh][t][d] -> vct[bh][d][compact_i]
// ---------------------------------------------------------------------------
__global__ __launch_bounds__(256) void gather_vT(
    const f16* __restrict__ vb, const int* __restrict__ cidx,
    const int* __restrict__ ccnt, f16* __restrict__ vct)
{
    __shared__ f16 Vl[64][72];
    const int bh = blockIdx.y, b = bh / NH;
    const int i0 = blockIdx.x * 64;
    if (i0 >= ccnt[b]) return;
    const int tid = threadIdx.x;
    const size_t base = (size_t)bh * T_LEN * DH;

#pragma unroll
    for (int half = 0; half < 2; ++half) {
        const int c = half * 256 + tid;
        const int row = c >> 3, cc = c & 7;
        const int src = cidx[b * T_LEN + i0 + row];
        *(int4*)&Vl[row][cc * 8] =
            *(const int4*)(vb + base + (size_t)src * DH + cc * 8);
    }
    __syncthreads();
    const int dr = tid >> 2, ic = tid & 3;
    f16 tmp[16];
#pragma unroll
    for (int jj = 0; jj < 16; ++jj) tmp[jj] = Vl[ic * 16 + jj][dr];
    f16* dst = vct + ((size_t)bh * DH + dr) * T_LEN + i0 + ic * 16;
    *(int4*)(dst)     = *(int4*)&tmp[0];
    *(int4*)(dst + 8) = *(int4*)&tmp[8];
}

// ---------------------------------------------------------------------------
// MFMA flash attention v4: ZERO LDS, ZERO barriers. All operands read
// directly from global (K/V^T are L2/L3-resident: 24 MB total). Swapped
// S^T = mfma(K,Q) keeps softmax lane-local; P in registers feeds
// O^T += mfma(V^T, P) via 16x16x16. 4 independent waves per block.
// ---------------------------------------------------------------------------
__global__ __launch_bounds__(256, 3) void attn_mfma(
    const f16* __restrict__ qh, const f16* __restrict__ kcb,
    const f16* __restrict__ vct, const float* __restrict__ cbias,
    const int* __restrict__ ccnt, f16* __restrict__ abh)
{
    const int bh = blockIdx.y, b = bh / NH, h = bh % NH;
    const int tid = threadIdx.x, w = tid >> 6, l = tid & 63;
    const int lg = l >> 4, lr = l & 15;
    const size_t base = (size_t)bh * T_LEN * DH;
    const int q0 = blockIdx.x * 128 + w * 32;

    // Q fragments (B operand of S^T; lane->row/k map identical to A)
    f16x8 qf[2][2];
#pragma unroll
    for (int mi = 0; mi < 2; ++mi)
#pragma unroll
        for (int ki = 0; ki < 2; ++ki)
            qf[mi][ki] = *(const f16x8*)(qh + base +
                (size_t)(q0 + mi * 16 + lr) * DH + ki * 32 + lg * 8);

    f32x4 o[4][2];   // O^T tiles: [d-tile][q-tile]
#pragma unroll
    for (int dt = 0; dt < 4; ++dt)
#pragma unroll
        for (int mi = 0; mi < 2; ++mi) o[dt][mi] = (f32x4)(0.f);
    float m_[2] = {-1e30f, -1e30f}, l_[2] = {0.f, 0.f};

    const int npad = ccnt[b];
    const float* biasp = cbias + b * T_LEN;
    const f16* kbase = kcb + base;
    const f16* vtbase = vct + (size_t)bh * DH * T_LEN;

    for (int i0 = 0; i0 < npad; i0 += 64) {
        // --- S^T = K Q^T : C rows = src, cols = q.  K frags from global ---
        f32x4 s[4][2];
#pragma unroll
        for (int ni = 0; ni < 4; ++ni)
#pragma unroll
            for (int mi = 0; mi < 2; ++mi) s[ni][mi] = (f32x4)(0.f);
#pragma unroll
        for (int ni = 0; ni < 4; ++ni) {
            const int row = i0 + ni * 16 + lr;
#pragma unroll
            for (int ki = 0; ki < 2; ++ki) {
                const f16x8 kf = *(const f16x8*)(kbase +
                    (size_t)row * DH + ki * 32 + lg * 8);
#pragma unroll
                for (int mi = 0; mi < 2; ++mi)
                    s[ni][mi] = MFMA32(kf, qf[mi][ki], s[ni][mi]);
            }
        }

        // --- bias per lane (src = i0 + ni*16 + lg*4 + rg) ---
        float bv[4][4];
#pragma unroll
        for (int ni = 0; ni < 4; ++ni) {
            const float4 b4 = *(const float4*)(biasp + i0 + ni * 16 + lg * 4);
            bv[ni][0] = b4.x; bv[ni][1] = b4.y; bv[ni][2] = b4.z; bv[ni][3] = b4.w;
        }

        // --- softmax per q-col tile mi (16 lane-local vals + 2 shfl) ---
        f16x4 pk[2][4];
        float r_[2];
#pragma unroll
        for (int mi = 0; mi < 2; ++mi) {
            float sv[4][4];
            float mx = -1e30f;
#pragma unroll
            for (int ni = 0; ni < 4; ++ni)
#pragma unroll
                for (int rg = 0; rg < 4; ++rg) {
                    sv[ni][rg] = s[ni][mi][rg] + bv[ni][rg];
                    mx = fmaxf(mx, sv[ni][rg]);
                }
            mx = fmaxf(mx, __shfl_xor(mx, 16));
            mx = fmaxf(mx, __shfl_xor(mx, 32));
            const float newm = fmaxf(m_[mi], mx);
            r_[mi] = __expf(m_[mi] - newm);
            m_[mi] = newm;
            float ps = 0.f;
#pragma unroll
            for (int ni = 0; ni < 4; ++ni) {
                float p0 = __expf(sv[ni][0] - newm);
                float p1 = __expf(sv[ni][1] - newm);
                float p2 = __expf(sv[ni][2] - newm);
                float p3 = __expf(sv[ni][3] - newm);
                ps += (p0 + p1) + (p2 + p3);
                pk[mi][ni] = (f16x4){(f16)p0, (f16)p1, (f16)p2, (f16)p3};
            }
            ps += __shfl_xor(ps, 16);
            ps += __shfl_xor(ps, 32);
            l_[mi] = l_[mi] * r_[mi] + ps;
        }

        // --- rescale O^T ---
#pragma unroll
        for (int dt = 0; dt < 4; ++dt)
#pragma unroll
            for (int mi = 0; mi < 2; ++mi)
#pragma unroll
                for (int rg = 0; rg < 4; ++rg) o[dt][mi][rg] *= r_[mi];

        // --- O^T += V^T P (16x16x16; A = V^T frags from global) ---
#pragma unroll
        for (int dt = 0; dt < 4; ++dt) {
            const int row = dt * 16 + lr;
#pragma unroll
            for (int ni = 0; ni < 4; ++ni) {
                const f16x4 vf = *(const f16x4*)(vtbase +
                    (size_t)row * T_LEN + i0 + ni * 16 + lg * 4);
#pragma unroll
                for (int mi = 0; mi < 2; ++mi)
                    o[dt][mi] = MFMA16(vf, pk[mi][ni], o[dt][mi]);
            }
        }
    }

    // --- epilogue: O^T lane holds (d = dt*16+lg*4+rg, q = mi*16+lr) ---
#pragma unroll
    for (int mi = 0; mi < 2; ++mi) {
        const float inv = 1.f / l_[mi];
        const int q = q0 + mi * 16 + lr;
#pragma unroll
        for (int dt = 0; dt < 4; ++dt) {
            const int d0 = dt * 16 + lg * 4;
            f16x4 ov = {(f16)(o[dt][mi][0] * inv), (f16)(o[dt][mi][1] * inv),
                        (f16)(o[dt][mi][2] * inv), (f16)(o[dt][mi][3] * inv)};
            *(f16x4*)(abh + (size_t)(q * BSZ + b) * EMB + h * DH + d0) = ov;
        }
    }
}

// ---------------------------------------------------------------------------
extern "C" void kernel_launch(void* const* d_in, const int* in_sizes, int n_in,
                              void* d_out, int out_size, void* d_ws, size_t ws_size,
                              hipStream_t stream)
{
    const float* x     = (const float*)d_in[0];
    const int*   mask  = (const int*)d_in[1];
    const float* abias = (const float*)d_in[2];
    const float* wqkv  = (const float*)d_in[3];
    const float* bqkv  = (const float*)d_in[4];
    const float* wout  = (const float*)d_in[5];
    const float* bout  = (const float*)d_in[6];
    float* out = (float*)d_out;

    const int n_x  = NTOK * EMB;
    const int n_wq = N_QKV * EMB;
    const int n_wo = EMB * EMB;
    const size_t per = (size_t)BH * T_LEN * DH;   // 6,291,456 f16

    f16* xh    = (f16*)d_ws;
    f16* wqkvh = xh + n_x;
    f16* wouth = wqkvh + n_wq;
    f16* qhb   = wouth + n_wo;
    f16* kcb   = qhb + per;    // compacted K
    f16* vhb   = kcb + per;    // V (t-order)
    f16* abh   = vhb + per;
    f16* vct   = abh + per;    // V^T compacted [bh][d][i]
    float* cbias = (float*)(vct + per);
    int*   cidx  = (int*)(cbias + BSZ * T_LEN);
    int*   imap  = cidx + BSZ * T_LEN;
    int*   ccnt  = imap + BSZ * T_LEN;

    conv_compact<<<CONVB + BSZ, 256, 0, stream>>>(
        x, wqkv, wout, xh, mask, abias, cidx, cbias, imap, ccnt);

    gemm_h<1><<<dim3(NTOK / 128, N_QKV / 128), 256, 0, stream>>>(
        xh, wqkvh, bqkv, nullptr, qhb, kcb, vhb, imap, NTOK, N_QKV, EMB);

    gather_vT<<<dim3(T_LEN / 64, BH), 256, 0, stream>>>(vhb, cidx, ccnt, vct);

    attn_mfma<<<dim3(T_LEN / 128, BH), 256, 0, stream>>>(
        qhb, kcb, vct, cbias, ccnt, abh);

    gemm_h<0><<<dim3(NTOK / 128, EMB / 128), 256, 0, stream>>>(
        abh, wouth, bout, out, nullptr, nullptr, nullptr, nullptr,
        NTOK, EMB, EMB);
}

// Round 11
// 248.156 us; speedup vs baseline: 1.4063x; 1.4063x over previous
//
#include <hip/hip_runtime.h>
#include <math.h>

#define T_LEN 2048
#define BSZ   4
#define EMB   768
#define NH    12
#define DH    64
#define NTOK  (T_LEN * BSZ)      // 8192
#define N_QKV (3 * EMB)          // 2304
#define BH    (BSZ * NH)         // 48
#define CONVB 8448               // (n_x + n_wq + n_wo)/4/256
#define LOG2E 1.44269504f

typedef _Float16 f16;
typedef _Float16 f16x8 __attribute__((ext_vector_type(8)));
typedef _Float16 f16x4 __attribute__((ext_vector_type(4)));
typedef float    f32x4 __attribute__((ext_vector_type(4)));

#define MFMA32(a, b, c) __builtin_amdgcn_mfma_f32_16x16x32_f16(a, b, c, 0, 0, 0)
#define MFMA16(a, b, c) __builtin_amdgcn_mfma_f32_16x16x16f16(a, b, c, 0, 0, 0)

// async global->LDS, 16B per lane; LDS dest = wave-uniform base + lane*16
__device__ __forceinline__ void gload16(const void* g, void* l) {
    __builtin_amdgcn_global_load_lds(
        (const __attribute__((address_space(1))) void*)g,
        (__attribute__((address_space(3))) void*)l, 16, 0, 0);
}

// ---------------------------------------------------------------------------
// Fused: fp32->fp16 conversion (blocks 0..CONVB-1) + mask compaction.
// cbias is stored PRE-MULTIPLIED by log2(e) (softmax uses exp2).
// ---------------------------------------------------------------------------
__global__ __launch_bounds__(256) void conv_compact(
    const float* __restrict__ s0, const float* __restrict__ s1,
    const float* __restrict__ s2, f16* __restrict__ dst,
    const int* __restrict__ mask, const float* __restrict__ abias,
    int* __restrict__ cidx, float* __restrict__ cbias,
    int* __restrict__ imap, int* __restrict__ ccount)
{
    const int tid = threadIdx.x;
    if (blockIdx.x < CONVB) {
        const int n0 = NTOK * EMB, n1 = N_QKV * EMB, n2 = EMB * EMB;
        const int i = (blockIdx.x * 256 + tid) * 4;
        const int t01 = n0 + n1;
        const float* s;
        int off;
        if (i < n0)            { s = s0; off = i; }
        else if (i < t01)      { s = s1; off = i - n0; }
        else if (i < t01 + n2) { s = s2; off = i - t01; }
        else return;
        const float4 v = *(const float4*)(s + off);
        f16 hv[4] = {(f16)v.x, (f16)v.y, (f16)v.z, (f16)v.w};
        *(double*)(dst + i) = *(double*)hv;
        return;
    }

    // ---- compaction ----
    const int b = blockIdx.x - CONVB;
    __shared__ int cnt[32], off_l[32], tot[2];
    const int wv = tid >> 6, lane = tid & 63;
    int* ip = cidx + b * T_LEN;
    float* bp = cbias + b * T_LEN;
    int* mp = imap + b * T_LEN;

    for (int i = 0; i < 8; ++i) {
        const int c = wv * 8 + i;
        const int s = c * 64 + lane;
        const int mv = mask[s * BSZ + b];
        const unsigned long long bal = __ballot(mv == 0);
        if (lane == 0) cnt[c] = __popcll(bal);
    }
    __syncthreads();
    if (tid == 0) {
        int acc = 0;
        for (int c = 0; c < 32; ++c) { off_l[c] = acc; acc += cnt[c]; }
        const int npad = (acc + 63) & ~63;
        tot[0] = acc; tot[1] = npad;
        ccount[b] = npad;
    }
    __syncthreads();
    for (int i = 0; i < 8; ++i) {
        const int c = wv * 8 + i;
        const int s = c * 64 + lane;
        const int mv = mask[s * BSZ + b];
        const float bv = abias[s * BSZ + b];
        const unsigned long long bal = __ballot(mv == 0);
        const int pos = __popcll(bal & ((1ull << lane) - 1ull));
        const int basec = off_l[c];
        if (mv == 0) {
            ip[basec + pos] = s;
            bp[basec + pos] = bv * LOG2E;     // log2 units
            mp[s] = basec + pos;
        } else mp[s] = -1;
    }
    const int baseT = tot[0], npad = tot[1];
    if (tid < npad - baseT) { ip[baseT + tid] = 0; bp[baseT + tid] = -1e30f; }
}

// ---------------------------------------------------------------------------
// fp16 MFMA GEMM (m97 structure): global_load_lds(16B), linear LDS [128][32]
// with source-side XOR swizzle, same XOR on frag reads.
// MODE 0: C fp32 MxN.
// MODE 1: q->qb * (0.125*log2e) [log2-unit scores]; k->kc[bh][imap(t)][d];
//         v->vb[bh][t][d]
// ---------------------------------------------------------------------------
template <int MODE>
__global__ __launch_bounds__(256) void gemm_h(
    const f16* __restrict__ A, const f16* __restrict__ W,
    const float* __restrict__ bias, float* __restrict__ C,
    f16* __restrict__ qb, f16* __restrict__ kc, f16* __restrict__ vb,
    const int* __restrict__ imap, int M, int N, int K)
{
    __shared__ __align__(16) f16 As[128][32];
    __shared__ __align__(16) f16 Bs[128][32];

    const int tid = threadIdx.x;
    const int w = tid >> 6, l = tid & 63;
    const int wr = w >> 1, wc = w & 1;
    const int lg = l >> 4, lr = l & 15;

    const int bm = blockIdx.x * 128, bn = blockIdx.y * 128;

    int srow[2], sqc[2];
#pragma unroll
    for (int it = 0; it < 2; ++it) {
        const int c = w * 128 + it * 64 + l;
        srow[it] = c >> 2;
        sqc[it] = (c & 3) ^ ((srow[it] >> 1) & 3);
    }

    f32x4 acc[4][4];
#pragma unroll
    for (int i = 0; i < 4; ++i)
#pragma unroll
        for (int j = 0; j < 4; ++j) acc[i][j] = (f32x4)(0.f);

    const int cq = lg ^ ((lr >> 1) & 3);

    for (int kt = 0; kt < K; kt += 32) {
        __syncthreads();
#pragma unroll
        for (int it = 0; it < 2; ++it) {
            const int ldsb = (w * 128 + it * 64) * 16;
            gload16(A + (size_t)(bm + srow[it]) * K + kt + sqc[it] * 8,
                    (char*)&As[0][0] + ldsb);
            gload16(W + (size_t)(bn + srow[it]) * K + kt + sqc[it] * 8,
                    (char*)&Bs[0][0] + ldsb);
        }
        __syncthreads();

        f16x8 af[4], bf[4];
#pragma unroll
        for (int am = 0; am < 4; ++am)
            af[am] = *(const f16x8*)((const char*)&As[0][0] +
                     (wr * 64 + am * 16 + lr) * 64 + cq * 16);
#pragma unroll
        for (int bnf = 0; bnf < 4; ++bnf)
            bf[bnf] = *(const f16x8*)((const char*)&Bs[0][0] +
                      (wc * 64 + bnf * 16 + lr) * 64 + cq * 16);
#pragma unroll
        for (int am = 0; am < 4; ++am)
#pragma unroll
            for (int bnf = 0; bnf < 4; ++bnf)
                acc[am][bnf] = MFMA32(af[am], bf[bnf], acc[am][bnf]);
    }

    const int colb = bn + wc * 64;
    const int rowb = bm + wr * 64;
    float bv[4];
#pragma unroll
    for (int j = 0; j < 4; ++j) bv[j] = bias[colb + j * 16 + lr];

    if (MODE == 0) {
#pragma unroll
        for (int am = 0; am < 4; ++am)
#pragma unroll
            for (int bnf = 0; bnf < 4; ++bnf)
#pragma unroll
                for (int rg = 0; rg < 4; ++rg) {
                    const int row = rowb + am * 16 + lg * 4 + rg;
                    const int col = colb + bnf * 16 + lr;
                    C[(size_t)row * N + col] = acc[am][bnf][rg] + bv[bnf];
                }
    } else {
        const int sec = bn / EMB;
        const float scale = (sec == 0) ? (0.125f * LOG2E) : 1.0f;
#pragma unroll
        for (int bnf = 0; bnf < 4; ++bnf) {
            const int col = colb + bnf * 16 + lr;
            const int e = col - sec * EMB;
            const int h = e >> 6, d = e & 63;
#pragma unroll
            for (int am = 0; am < 4; ++am)
#pragma unroll
                for (int rg = 0; rg < 4; ++rg) {
                    const int row = rowb + am * 16 + lg * 4 + rg;
                    const int t = row >> 2, bb = row & 3;
                    const f16 val = (f16)((acc[am][bnf][rg] + bv[bnf]) * scale);
                    if (sec == 0) {
                        qb[((size_t)((bb * NH + h) * T_LEN + t)) * DH + d] = val;
                    } else if (sec == 1) {
                        const int ipv = imap[bb * T_LEN + t];
                        if (ipv >= 0)
                            kc[((size_t)((bb * NH + h) * T_LEN + ipv)) * DH + d] = val;
                    } else {
                        vb[((size_t)((bb * NH + h) * T_LEN + t)) * DH + d] = val;
                    }
                }
        }
    }
}

// ---------------------------------------------------------------------------
// One-time V gather + transpose: vb[bh][t][d] -> vct[bh][d][compact_i]
// ---------------------------------------------------------------------------
__global__ __launch_bounds__(256) void gather_vT(
    const f16* __restrict__ vb, const int* __restrict__ cidx,
    const int* __restrict__ ccnt, f16* __restrict__ vct)
{
    __shared__ f16 Vl[64][72];
    const int bh = blockIdx.y, b = bh / NH;
    const int i0 = blockIdx.x * 64;
    if (i0 >= ccnt[b]) return;
    const int tid = threadIdx.x;
    const size_t base = (size_t)bh * T_LEN * DH;

#pragma unroll
    for (int half = 0; half < 2; ++half) {
        const int c = half * 256 + tid;
        const int row = c >> 3, cc = c & 7;
        const int src = cidx[b * T_LEN + i0 + row];
        *(int4*)&Vl[row][cc * 8] =
            *(const int4*)(vb + base + (size_t)src * DH + cc * 8);
    }
    __syncthreads();
    const int dr = tid >> 2, ic = tid & 3;
    f16 tmp[16];
#pragma unroll
    for (int jj = 0; jj < 16; ++jj) tmp[jj] = Vl[ic * 16 + jj][dr];
    f16* dst = vct + ((size_t)bh * DH + dr) * T_LEN + i0 + ic * 16;
    *(int4*)(dst)     = *(int4*)&tmp[0];
    *(int4*)(dst + 8) = *(int4*)&tmp[8];
}

// ---------------------------------------------------------------------------
// MFMA flash attention v5: back to LDS-staged (R6 base), now 8 waves x 16 q
// per 512-thread block (128 q). Swapped S^T = mfma(K,Q), lane-local softmax
// (exp2, log2-unit scores), defer-max (THR=11 log2), register-resident P
// feeding O^T += mfma(V^T, P) 16x16x16. 1 barrier/tile, double-buffered.
// ---------------------------------------------------------------------------
__global__ __launch_bounds__(512, 4) void attn_mfma(
    const f16* __restrict__ qh, const f16* __restrict__ kcb,
    const f16* __restrict__ vct, const float* __restrict__ cbias,
    const int* __restrict__ ccnt, f16* __restrict__ abh)
{
    __shared__ __align__(16) f16 Kt[2][64][64];   // [buf][src][d]
    __shared__ __align__(16) f16 Vt[2][64][64];   // [buf][d][src]
    __shared__ float bias_l[2][64];

    const int bh = blockIdx.y, b = bh / NH, h = bh % NH;
    const int tid = threadIdx.x, w = tid >> 6, l = tid & 63;
    const int lg = l >> 4, lr = l & 15;
    const size_t base = (size_t)bh * T_LEN * DH;
    const int q0 = blockIdx.x * 128 + w * 16;

    // Q fragments (B operand of S^T)
    f16x8 qf[2];
#pragma unroll
    for (int ki = 0; ki < 2; ++ki)
        qf[ki] = *(const f16x8*)(qh + base +
            (size_t)(q0 + lr) * DH + ki * 32 + lg * 8);

    f32x4 o[4];
#pragma unroll
    for (int dt = 0; dt < 4; ++dt) o[dt] = (f32x4)(0.f);
    float m_ = -1e30f, l_ = 0.f;

    const int npad = ccnt[b];
    const float* biasp = cbias + b * T_LEN;
    const f16* kbase = kcb + base;
    const f16* vtbase = vct + (size_t)bh * DH * T_LEN;

    // staging: thread stages one 16B chunk of Kt and one of Vt.
    const int srow = tid >> 3;                 // 0..63
    const int scc  = (tid & 7) ^ (srow & 7);   // source-side XOR swizzle
    const int ldsb = w * 1024;                 // wave-uniform dest base

    auto stage = [&](int buf, int i0s) {
        gload16(kbase + (size_t)(i0s + srow) * DH + scc * 8,
                (char*)&Kt[buf][0][0] + ldsb);
        gload16(vtbase + (size_t)srow * T_LEN + i0s + scc * 8,
                (char*)&Vt[buf][0][0] + ldsb);
        if (tid < 64) bias_l[buf][tid] = biasp[i0s + tid];
    };

    stage(0, 0);
    __syncthreads();

    int cur = 0;
    for (int i0 = 0; i0 < npad; i0 += 64, cur ^= 1) {
        if (i0 + 64 < npad) stage(cur ^ 1, i0 + 64);

        // --- S^T = K Q^T : C rows = src, cols = q ---
        f32x4 s[4];
#pragma unroll
        for (int ni = 0; ni < 4; ++ni) s[ni] = (f32x4)(0.f);
#pragma unroll
        for (int ni = 0; ni < 4; ++ni) {
            const int row = ni * 16 + lr;
#pragma unroll
            for (int ki = 0; ki < 2; ++ki) {
                const int cq = (ki * 4 + lg) ^ (row & 7);
                const f16x8 kf = *(const f16x8*)((const char*)&Kt[cur][0][0] +
                                 row * 128 + cq * 16);
                s[ni] = MFMA32(kf, qf[ki], s[ni]);
            }
        }

        // --- bias + max (lane-local 16 values, 2 shfl) ---
        float sv[4][4];
        float mx = -1e30f;
#pragma unroll
        for (int ni = 0; ni < 4; ++ni) {
            const float4 b4 = *(const float4*)&bias_l[cur][ni * 16 + lg * 4];
            sv[ni][0] = s[ni][0] + b4.x;
            sv[ni][1] = s[ni][1] + b4.y;
            sv[ni][2] = s[ni][2] + b4.z;
            sv[ni][3] = s[ni][3] + b4.w;
            mx = fmaxf(mx, fmaxf(fmaxf(sv[ni][0], sv[ni][1]),
                                 fmaxf(sv[ni][2], sv[ni][3])));
        }
        mx = fmaxf(mx, __shfl_xor(mx, 16));
        mx = fmaxf(mx, __shfl_xor(mx, 32));

        // --- defer-max: only rescale when max grew past THR (log2 units) ---
        if (!__all(mx <= m_ + 11.0f)) {
            const float newm = fmaxf(m_, mx);
            const float r = exp2f(m_ - newm);
            l_ *= r;
#pragma unroll
            for (int dt = 0; dt < 4; ++dt)
#pragma unroll
                for (int rg = 0; rg < 4; ++rg) o[dt][rg] *= r;
            m_ = newm;
        }

        f16x4 pk[4];
        float ps = 0.f;
#pragma unroll
        for (int ni = 0; ni < 4; ++ni) {
            const float p0 = exp2f(sv[ni][0] - m_);
            const float p1 = exp2f(sv[ni][1] - m_);
            const float p2 = exp2f(sv[ni][2] - m_);
            const float p3 = exp2f(sv[ni][3] - m_);
            ps += (p0 + p1) + (p2 + p3);
            pk[ni] = (f16x4){(f16)p0, (f16)p1, (f16)p2, (f16)p3};
        }
        ps += __shfl_xor(ps, 16);
        ps += __shfl_xor(ps, 32);
        l_ += ps;

        // --- O^T += V^T P (16x16x16; k-step ni over src) ---
#pragma unroll
        for (int dt = 0; dt < 4; ++dt) {
            const int row = dt * 16 + lr;
#pragma unroll
            for (int ni = 0; ni < 4; ++ni) {
                const int swc = (ni * 2 + (lg >> 1)) ^ (row & 7);
                const f16x4 vf = *(const f16x4*)((const char*)&Vt[cur][0][0] +
                                 row * 128 + swc * 16 + (lg & 1) * 8);
                o[dt] = MFMA16(vf, pk[ni], o[dt]);
            }
        }
        __syncthreads();
    }

    // --- epilogue: lane holds (d = dt*16+lg*4+rg, q = lr) ---
    const float inv = 1.f / l_;
    const int q = q0 + lr;
#pragma unroll
    for (int dt = 0; dt < 4; ++dt) {
        const int d0 = dt * 16 + lg * 4;
        f16x4 ov = {(f16)(o[dt][0] * inv), (f16)(o[dt][1] * inv),
                    (f16)(o[dt][2] * inv), (f16)(o[dt][3] * inv)};
        *(f16x4*)(abh + (size_t)(q * BSZ + b) * EMB + h * DH + d0) = ov;
    }
}

// ---------------------------------------------------------------------------
extern "C" void kernel_launch(void* const* d_in, const int* in_sizes, int n_in,
                              void* d_out, int out_size, void* d_ws, size_t ws_size,
                              hipStream_t stream)
{
    const float* x     = (const float*)d_in[0];
    const int*   mask  = (const int*)d_in[1];
    const float* abias = (const float*)d_in[2];
    const float* wqkv  = (const float*)d_in[3];
    const float* bqkv  = (const float*)d_in[4];
    const float* wout  = (const float*)d_in[5];
    const float* bout  = (const float*)d_in[6];
    float* out = (float*)d_out;

    const int n_x  = NTOK * EMB;
    const int n_wq = N_QKV * EMB;
    const int n_wo = EMB * EMB;
    const size_t per = (size_t)BH * T_LEN * DH;   // 6,291,456 f16

    f16* xh    = (f16*)d_ws;
    f16* wqkvh = xh + n_x;
    f16* wouth = wqkvh + n_wq;
    f16* qhb   = wouth + n_wo;
    f16* kcb   = qhb + per;    // compacted K
    f16* vhb   = kcb + per;    // V (t-order)
    f16* abh   = vhb + per;
    f16* vct   = abh + per;    // V^T compacted [bh][d][i]
    float* cbias = (float*)(vct + per);
    int*   cidx  = (int*)(cbias + BSZ * T_LEN);
    int*   imap  = cidx + BSZ * T_LEN;
    int*   ccnt  = imap + BSZ * T_LEN;

    conv_compact<<<CONVB + BSZ, 256, 0, stream>>>(
        x, wqkv, wout, xh, mask, abias, cidx, cbias, imap, ccnt);

    gemm_h<1><<<dim3(NTOK / 128, N_QKV / 128), 256, 0, stream>>>(
        xh, wqkvh, bqkv, nullptr, qhb, kcb, vhb, imap, NTOK, N_QKV, EMB);

    gather_vT<<<dim3(T_LEN / 64, BH), 256, 0, stream>>>(vhb, cidx, ccnt, vct);

    attn_mfma<<<dim3(T_LEN / 128, BH), 512, 0, stream>>>(
        qhb, kcb, vct, cbias, ccnt, abh);

    gemm_h<0><<<dim3(NTOK / 128, EMB / 128), 256, 0, stream>>>(
        abh, wouth, bout, out, nullptr, nullptr, nullptr, nullptr,
        NTOK, EMB, EMB);
}